// Round 1
// baseline (71.794 us; speedup 1.0000x reference)
//
#include <hip/hip_runtime.h>
#include <hip/hip_bf16.h>

#define NROWS 4096
#define DIM   1024
#define BN    128   // columns per block
#define BM    128   // rows per tile
#define BK    64    // K-step
#define RPB   256   // rows per block (row-split)
#define TEMP_INV 10.0f

typedef __bf16 bf16x8 __attribute__((ext_vector_type(8)));
typedef float  f32x4  __attribute__((ext_vector_type(4)));

__device__ __forceinline__ void gload16(const void* g, void* l) {
    __builtin_amdgcn_global_load_lds(
        (const __attribute__((address_space(1))) void*)g,
        (__attribute__((address_space(3))) void*)l, 16, 0, 0);
}

__device__ __forceinline__ unsigned short f2bf(float f) {
    __hip_bfloat16 h = __float2bfloat16(f);
    return *reinterpret_cast<unsigned short*>(&h);
}

// Row-normalize fp32 -> bf16.  One block (256 thr) per row; float4 loads.
__global__ __launch_bounds__(256) void normalize_k(const float* __restrict__ pred,
                                                   unsigned short* __restrict__ xn) {
    const int row = blockIdx.x;
    const int tid = threadIdx.x;
    const float4 v = reinterpret_cast<const float4*>(pred + (size_t)row * DIM)[tid];
    float ss = v.x * v.x + v.y * v.y + v.z * v.z + v.w * v.w;
    #pragma unroll
    for (int off = 32; off; off >>= 1) ss += __shfl_xor(ss, off, 64);
    __shared__ float red[4];
    if ((tid & 63) == 0) red[tid >> 6] = ss;
    __syncthreads();
    const float tot = red[0] + red[1] + red[2] + red[3];
    const float scale = 1.0f / fmaxf(sqrtf(tot), 1e-8f);
    ushort4 o;
    o.x = f2bf(v.x * scale);
    o.y = f2bf(v.y * scale);
    o.z = f2bf(v.z * scale);
    o.w = f2bf(v.w * scale);
    reinterpret_cast<ushort4*>(xn + (size_t)row * DIM)[tid] = o;
}

// Fused Gram-GEMM + contrastive epilogue.
// Block = 256 thr = 4 waves (2x2 of 64x64).  Tile 128x128, BK=64.
// blockIdx.x: column block (BN cols), blockIdx.y: row split (RPB rows).
__global__ __launch_bounds__(256, 2) void fused_gram(
        const unsigned short* __restrict__ xn, const int* __restrict__ tgt,
        float* __restrict__ posw, float* __restrict__ denw, float* __restrict__ cntw) {
    __shared__ unsigned short As[BM * BK];
    __shared__ unsigned short Bs[BN * BK];

    const int tid  = threadIdx.x;
    const int w    = tid >> 6;
    const int l    = tid & 63;
    const int wrow = w >> 1;
    const int wcol = w & 1;
    const int colbase  = blockIdx.x * BN;
    const int rowbase0 = blockIdx.y * RPB;

    // Per-lane column indices / classes (4 columns per lane, one per fj).
    int jc[4], tj[4];
    #pragma unroll
    for (int fj = 0; fj < 4; ++fj) {
        jc[fj] = colbase + wcol * 64 + fj * 16 + (l & 15);
        tj[fj] = tgt[jc[fj]];
    }

    float den[4] = {0.f, 0.f, 0.f, 0.f};
    float pos[4] = {0.f, 0.f, 0.f, 0.f};
    float cnt[4] = {0.f, 0.f, 0.f, 0.f};

    // Staging address components (byte layout: chunk c -> lds elem c*2048 + tid*8)
    const int srow = tid >> 3;          // 0..31
    const int skcol = (tid & 7) * 8;    // 0..56

    for (int mt = 0; mt < RPB / BM; ++mt) {
        const int rowbase = rowbase0 + mt * BM;

        f32x4 acc[4][4];
        #pragma unroll
        for (int i = 0; i < 4; ++i)
            #pragma unroll
            for (int j = 0; j < 4; ++j)
                acc[i][j] = (f32x4){0.f, 0.f, 0.f, 0.f};

        for (int kt = 0; kt < DIM / BK; ++kt) {
            const int k0 = kt * BK;
            __syncthreads();   // previous compute done before LDS overwrite
            #pragma unroll
            for (int c = 0; c < 4; ++c) {
                const int r = c * 32 + srow;
                gload16(xn + (size_t)(rowbase + r) * DIM + k0 + skcol,
                        &As[c * 2048 + tid * 8]);
                gload16(xn + (size_t)(colbase + r) * DIM + k0 + skcol,
                        &Bs[c * 2048 + tid * 8]);
            }
            __syncthreads();   // compiler drains vmcnt before barrier

            #pragma unroll
            for (int ks = 0; ks < 2; ++ks) {
                bf16x8 a[4], b[4];
                #pragma unroll
                for (int fi = 0; fi < 4; ++fi)
                    a[fi] = *reinterpret_cast<const bf16x8*>(
                        &As[(wrow * 64 + fi * 16 + (l & 15)) * BK + ks * 32 + (l >> 4) * 8]);
                #pragma unroll
                for (int fj = 0; fj < 4; ++fj)
                    b[fj] = *reinterpret_cast<const bf16x8*>(
                        &Bs[(wcol * 64 + fj * 16 + (l & 15)) * BK + ks * 32 + (l >> 4) * 8]);
                #pragma unroll
                for (int fi = 0; fi < 4; ++fi)
                    #pragma unroll
                    for (int fj = 0; fj < 4; ++fj)
                        acc[fi][fj] = __builtin_amdgcn_mfma_f32_16x16x32_bf16(
                            a[fi], b[fj], acc[fi][fj], 0, 0, 0);
            }
        }

        // Fused epilogue: C/D layout col=lane&15, row=(lane>>4)*4+q  [m89/m91]
        #pragma unroll
        for (int fi = 0; fi < 4; ++fi) {
            const int ribase = rowbase + wrow * 64 + fi * 16 + (l >> 4) * 4;
            const int4 tiv = *reinterpret_cast<const int4*>(&tgt[ribase]);
            const int tia[4] = {tiv.x, tiv.y, tiv.z, tiv.w};
            #pragma unroll
            for (int q = 0; q < 4; ++q) {
                const int gi = ribase + q;
                const int ti = tia[q];
                #pragma unroll
                for (int fj = 0; fj < 4; ++fj) {
                    const float s  = acc[fi][fj][q];
                    const float pc = fmaxf(s, 1e-10f);
                    const float e  = __expf(TEMP_INV * pc);
                    const bool same = (ti == tj[fj]);
                    if (!same) {
                        den[fj] += e;
                    } else if (gi != jc[fj]) {
                        pos[fj] += pc;
                        cnt[fj] += 1.0f;
                    }
                }
            }
        }
    }

    // Reduce across lanes sharing a column (lanes differing in bits 4,5).
    #pragma unroll
    for (int fj = 0; fj < 4; ++fj) {
        #pragma unroll
        for (int off = 16; off < 64; off <<= 1) {
            den[fj] += __shfl_xor(den[fj], off, 64);
            pos[fj] += __shfl_xor(pos[fj], off, 64);
            cnt[fj] += __shfl_xor(cnt[fj], off, 64);
        }
        if (l < 16) {
            atomicAdd(&denw[jc[fj]], den[fj]);
            atomicAdd(&posw[jc[fj]], pos[fj]);
            atomicAdd(&cntw[jc[fj]], cnt[fj]);
        }
    }
}

// Final per-column loss + reduction to scalar.
__global__ __launch_bounds__(256) void finalize_k(const float* __restrict__ posw,
                                                  const float* __restrict__ denw,
                                                  const float* __restrict__ cntw,
                                                  float* __restrict__ out) {
    const int j = blockIdx.x * 256 + threadIdx.x;
    const float d = fmaxf(denw[j], 1e-10f);
    float v = TEMP_INV * posw[j] - cntw[j] * __logf(d);
    #pragma unroll
    for (int off = 32; off; off >>= 1) v += __shfl_xor(v, off, 64);
    __shared__ float red[4];
    if ((threadIdx.x & 63) == 0) red[threadIdx.x >> 6] = v;
    __syncthreads();
    if (threadIdx.x == 0) {
        const float s = red[0] + red[1] + red[2] + red[3];
        atomicAdd(out, -s * (1.0f / 4096.0f));
    }
}

extern "C" void kernel_launch(void* const* d_in, const int* in_sizes, int n_in,
                              void* d_out, int out_size, void* d_ws, size_t ws_size,
                              hipStream_t stream) {
    const float* pred = (const float*)d_in[0];
    const int*   tgt  = (const int*)d_in[1];
    float* out = (float*)d_out;

    unsigned short* xn = (unsigned short*)d_ws;                       // 8 MB bf16
    float* posw = (float*)((char*)d_ws + (size_t)NROWS * DIM * 2);
    float* denw = posw + NROWS;
    float* cntw = denw + NROWS;

    hipMemsetAsync(posw, 0, 3 * NROWS * sizeof(float), stream);
    hipMemsetAsync(out, 0, sizeof(float), stream);

    normalize_k<<<NROWS, 256, 0, stream>>>(pred, xn);

    dim3 grid(NROWS / BN, NROWS / RPB);   // 32 x 16 = 512 blocks
    fused_gram<<<grid, 256, 0, stream>>>(xn, tgt, posw, denw, cntw);

    finalize_k<<<NROWS / 256, 256, 0, stream>>>(posw, denw, cntw, out);
}

// Round 2
// 65.132 us; speedup vs baseline: 1.1023x; 1.1023x over previous
//
#include <hip/hip_runtime.h>
#include <hip/hip_bf16.h>

#define NROWS 4096
#define DIM   1024
#define BT    128            // tile edge
#define BK    64             // K-step
#define NTB   (NROWS / BT)   // 32 tile-blocks per edge
#define TEMP_INV 10.0f

typedef __bf16 bf16x8 __attribute__((ext_vector_type(8)));
typedef float  f32x4  __attribute__((ext_vector_type(4)));

__device__ __forceinline__ void gload16(const void* g, void* l) {
    __builtin_amdgcn_global_load_lds(
        (const __attribute__((address_space(1))) void*)g,
        (__attribute__((address_space(3))) void*)l, 16, 0, 0);
}

__device__ __forceinline__ unsigned short f2bf(float f) {
    __hip_bfloat16 h = __float2bfloat16(f);
    return *reinterpret_cast<unsigned short*>(&h);
}

// Row-normalize fp32 -> bf16, plus class histogram (1 atomic per row).
__global__ __launch_bounds__(256) void normalize_k(const float* __restrict__ pred,
                                                   unsigned short* __restrict__ xn,
                                                   const int* __restrict__ tgt,
                                                   int* __restrict__ count) {
    const int row = blockIdx.x;
    const int tid = threadIdx.x;
    const float4 v = reinterpret_cast<const float4*>(pred + (size_t)row * DIM)[tid];
    float ss = v.x * v.x + v.y * v.y + v.z * v.z + v.w * v.w;
    #pragma unroll
    for (int off = 32; off; off >>= 1) ss += __shfl_xor(ss, off, 64);
    __shared__ float red[4];
    if ((tid & 63) == 0) red[tid >> 6] = ss;
    __syncthreads();
    const float tot = red[0] + red[1] + red[2] + red[3];
    const float scale = 1.0f / fmaxf(sqrtf(tot), 1e-8f);
    ushort4 o;
    o.x = f2bf(v.x * scale);
    o.y = f2bf(v.y * scale);
    o.z = f2bf(v.z * scale);
    o.w = f2bf(v.w * scale);
    reinterpret_cast<ushort4*>(xn + (size_t)row * DIM)[tid] = o;
    if (tid == 0) atomicAdd(&count[tgt[row]], 1);
}

// Fused symmetric Gram-GEMM + contrastive epilogue over upper-triangular tiles.
// Block = 256 thr = 4 waves (2x2 of 64x64).  Tile 128x128, BK=64.
// Off-diagonal tiles emit BOTH column-side and row-side (mirror) partials.
__global__ __launch_bounds__(256, 4) void fused_gram(
        const unsigned short* __restrict__ xn, const int* __restrict__ tgt,
        float* __restrict__ posw, float* __restrict__ denw) {
    __shared__ unsigned short As[BT * BK];
    __shared__ unsigned short Bs[BT * BK];

    // Decode linear block id -> (bi, bj), bi <= bj (uniform scalar loop).
    int bi = 0, rem = blockIdx.x;
    while (rem >= NTB - bi) { rem -= NTB - bi; ++bi; }
    const int bj = bi + rem;
    const bool diag = (bi == bj);
    const int rowbase = bi * BT;
    const int colbase = bj * BT;

    const int tid  = threadIdx.x;
    const int w    = tid >> 6;
    const int l    = tid & 63;
    const int wrow = w >> 1;
    const int wcol = w & 1;

    // Per-lane column indices / classes (one column per fj).
    int jc[4], tj[4];
    #pragma unroll
    for (int fj = 0; fj < 4; ++fj) {
        jc[fj] = colbase + wcol * 64 + fj * 16 + (l & 15);
        tj[fj] = tgt[jc[fj]];
    }

    f32x4 acc[4][4];
    #pragma unroll
    for (int i = 0; i < 4; ++i)
        #pragma unroll
        for (int j = 0; j < 4; ++j)
            acc[i][j] = (f32x4){0.f, 0.f, 0.f, 0.f};

    const int srow  = tid >> 3;        // 0..31
    const int skcol = (tid & 7) * 8;   // 0..56

    for (int kt = 0; kt < DIM / BK; ++kt) {
        const int k0 = kt * BK;
        __syncthreads();   // previous compute done before LDS overwrite
        #pragma unroll
        for (int c = 0; c < 4; ++c) {
            const int r = c * 32 + srow;
            gload16(xn + (size_t)(rowbase + r) * DIM + k0 + skcol,
                    &As[c * 2048 + tid * 8]);
        }
        if (!diag) {
            #pragma unroll
            for (int c = 0; c < 4; ++c) {
                const int r = c * 32 + srow;
                gload16(xn + (size_t)(colbase + r) * DIM + k0 + skcol,
                        &Bs[c * 2048 + tid * 8]);
            }
        }
        __syncthreads();

        const unsigned short* bs = diag ? As : Bs;
        #pragma unroll
        for (int ks = 0; ks < 2; ++ks) {
            bf16x8 a[4], b[4];
            #pragma unroll
            for (int fi = 0; fi < 4; ++fi)
                a[fi] = *reinterpret_cast<const bf16x8*>(
                    &As[(wrow * 64 + fi * 16 + (l & 15)) * BK + ks * 32 + (l >> 4) * 8]);
            #pragma unroll
            for (int fj = 0; fj < 4; ++fj)
                b[fj] = *reinterpret_cast<const bf16x8*>(
                    &bs[(wcol * 64 + fj * 16 + (l & 15)) * BK + ks * 32 + (l >> 4) * 8]);
            #pragma unroll
            for (int fi = 0; fi < 4; ++fi)
                #pragma unroll
                for (int fj = 0; fj < 4; ++fj)
                    acc[fi][fj] = __builtin_amdgcn_mfma_f32_16x16x32_bf16(
                        a[fi], b[fj], acc[fi][fj], 0, 0, 0);
        }
    }

    // Fused epilogue.  C/D layout: col = lane&15, row = (lane>>4)*4 + q  [m89/m91]
    float denc[4] = {0.f, 0.f, 0.f, 0.f};
    float posc[4] = {0.f, 0.f, 0.f, 0.f};

    #pragma unroll
    for (int fi = 0; fi < 4; ++fi) {
        const int ribase = rowbase + wrow * 64 + fi * 16 + (l >> 4) * 4;
        const int4 tiv = *reinterpret_cast<const int4*>(&tgt[ribase]);
        const int tia[4] = {tiv.x, tiv.y, tiv.z, tiv.w};
        float denr[4] = {0.f, 0.f, 0.f, 0.f};
        float posr[4] = {0.f, 0.f, 0.f, 0.f};
        #pragma unroll
        for (int q = 0; q < 4; ++q) {
            const int gi = ribase + q;
            const int ti = tia[q];
            #pragma unroll
            for (int fj = 0; fj < 4; ++fj) {
                const float s  = acc[fi][fj][q];
                const float pc = fmaxf(s, 1e-10f);
                const float e  = __expf(TEMP_INV * pc);
                if (ti != tj[fj]) {
                    denc[fj] += e;
                    denr[q]  += e;
                } else if (gi != jc[fj]) {
                    posc[fj] += pc;
                    posr[q]  += pc;
                }
            }
        }
        if (!diag) {
            // Row-side (mirror) reduction: lanes sharing a row differ in bits 0-3.
            #pragma unroll
            for (int q = 0; q < 4; ++q) {
                #pragma unroll
                for (int off = 1; off < 16; off <<= 1) {
                    denr[q] += __shfl_xor(denr[q], off, 64);
                    posr[q] += __shfl_xor(posr[q], off, 64);
                }
            }
            if ((l & 15) == 0) {
                #pragma unroll
                for (int q = 0; q < 4; ++q) {
                    atomicAdd(&denw[ribase + q], denr[q]);
                    atomicAdd(&posw[ribase + q], posr[q]);
                }
            }
        }
    }

    // Column-side reduction: lanes sharing a column differ in bits 4-5.
    #pragma unroll
    for (int fj = 0; fj < 4; ++fj) {
        #pragma unroll
        for (int off = 16; off < 64; off <<= 1) {
            denc[fj] += __shfl_xor(denc[fj], off, 64);
            posc[fj] += __shfl_xor(posc[fj], off, 64);
        }
        if (l < 16) {
            atomicAdd(&denw[jc[fj]], denc[fj]);
            atomicAdd(&posw[jc[fj]], posc[fj]);
        }
    }
}

// Final per-column loss + reduction to scalar.  cnt_j = count[t_j] - 1.
__global__ __launch_bounds__(256) void finalize_k(const float* __restrict__ posw,
                                                  const float* __restrict__ denw,
                                                  const int* __restrict__ tgt,
                                                  const int* __restrict__ count,
                                                  float* __restrict__ out) {
    const int j = blockIdx.x * 256 + threadIdx.x;
    const float d = fmaxf(denw[j], 1e-10f);
    const float c = (float)(count[tgt[j]] - 1);
    float v = TEMP_INV * posw[j] - c * __logf(d);
    #pragma unroll
    for (int off = 32; off; off >>= 1) v += __shfl_xor(v, off, 64);
    __shared__ float red[4];
    if ((threadIdx.x & 63) == 0) red[threadIdx.x >> 6] = v;
    __syncthreads();
    if (threadIdx.x == 0) {
        const float s = red[0] + red[1] + red[2] + red[3];
        atomicAdd(out, -s * (1.0f / 4096.0f));
    }
}

extern "C" void kernel_launch(void* const* d_in, const int* in_sizes, int n_in,
                              void* d_out, int out_size, void* d_ws, size_t ws_size,
                              hipStream_t stream) {
    const float* pred = (const float*)d_in[0];
    const int*   tgt  = (const int*)d_in[1];
    float* out = (float*)d_out;

    unsigned short* xn = (unsigned short*)d_ws;                      // 8 MB bf16
    float* posw = (float*)((char*)d_ws + (size_t)NROWS * DIM * 2);
    float* denw = posw + NROWS;
    int*   count = (int*)(denw + NROWS);                             // 128 ints

    hipMemsetAsync(posw, 0, (2 * NROWS + 128) * sizeof(float), stream);
    hipMemsetAsync(out, 0, sizeof(float), stream);

    normalize_k<<<NROWS, 256, 0, stream>>>(pred, xn, tgt, count);

    const int nblocks = NTB * (NTB + 1) / 2;   // 528 upper-triangular tiles
    fused_gram<<<nblocks, 256, 0, stream>>>(xn, tgt, posw, denw);

    finalize_k<<<NROWS / 256, 256, 0, stream>>>(posw, denw, tgt, count, out);
}